// Round 1
// baseline (132.549 us; speedup 1.0000x reference)
//
#include <hip/hip_runtime.h>
#include <math.h>

#define NW 1e-5f
#define PI_SQRT 1.7724538509055159f
#define TWO_SQRT 1.4142135623730951f
#define CUTOFF 3.0f

// ---------------------------------------------------------------------------
// Kernel 1: per-(b,m) parameter precompute + zero d_out.
// params[b*M+m] = {B_mean, c, coef = 2*A*c^2/sqrt(pi), rad = 3/c + slack}
// ---------------------------------------------------------------------------
__global__ void precompute_kernel(const float* __restrict__ rf,
                                  const float* __restrict__ width,
                                  const float* __restrict__ A_mean,
                                  const float* __restrict__ area,
                                  const float* __restrict__ sf,
                                  float4* __restrict__ params,
                                  float* __restrict__ out,
                                  int B, int M, int N, int out_total) {
    int idx = blockIdx.x * blockDim.x + threadIdx.x;
    if (idx < out_total) out[idx] = 0.0f;   // zero output (poisoned by harness)
    if (idx >= B * M) return;
    int b = idx / M;
    int m = idx - b * M;

    float r0 = rf[idx * 3 + 0];
    float r1 = rf[idx * 3 + 1];
    float r2 = rf[idx * 3 + 2];
    // exact 3-sort (descending) via min/max network
    float lo = fminf(r0, r1), hi = fmaxf(r0, r1);
    float B1 = fmaxf(hi, r2);
    float B3 = fminf(lo, r2);
    float B2 = fmaxf(lo, fminf(hi, r2));

    float w = width[idx];
    w = (w > NW) ? w : (w + NW);
    float inv_w = 1.0f / w;
    float d13 = (B1 - B3) * inv_w;
    float d23 = (B2 - B3) * inv_w;
    float d12 = (B1 - B2) * inv_w;
    float add_w_sq = (d13 * d13 + d23 * d23 + d12 * d12) * (1.0f / 9.0f);
    w = (w > 2.0f * NW) ? w : (w + 2.0f * NW);

    float sw = (sf[b * N + 1] - sf[b * N + 0]) * 0.5f;
    float ew = sqrtf(w * w * (1.0f + add_w_sq) + sw * sw);
    ew = (ew < sw * 0.5f) ? ew : (ew + sw * 0.5f);

    float bmean = (B1 + B2 + B3) * (1.0f / 3.0f);
    float c = TWO_SQRT / ew;
    float A = A_mean[idx] * area[m];
    float coef = 2.0f * A * c * c / PI_SQRT;
    float rad = CUTOFF / c + 0.02f;   // window radius in field units, + slack

    params[idx] = make_float4(bmean, c, coef, rad);
}

// ---------------------------------------------------------------------------
// Kernel 2: thread = one (b, n) field point; block = 256 consecutive n;
// grid.y = m-chunks (partial sums combined via atomicAdd).
// ---------------------------------------------------------------------------
__global__ __launch_bounds__(256) void spectra_kernel(
    const float4* __restrict__ params,
    const float* __restrict__ sf,
    float* __restrict__ out,
    int M, int N, int mchunk) {
    const int b = blockIdx.z;
    const int tile = blockIdx.x;
    const int n = tile * 256 + (int)threadIdx.x;
    if (n >= N) return;

    const float f = sf[b * N + n];
    // block's field range (grid is monotonically increasing)
    const int n_lo = tile * 256;
    const int n_hi = min(N - 1, tile * 256 + 255);
    const float fmin = sf[b * N + n_lo];
    const float fmax = sf[b * N + n_hi];

    const int m0 = blockIdx.y * mchunk;
    const int mend = min(mchunk, M - m0);
    const float4* __restrict__ p = params + (size_t)b * M + m0;

    float acc = 0.0f;
    for (int i = 0; i < mend; ++i) {
        float4 q = p[i];  // wave-uniform address -> scalar load
        // block-level window skip (uniform branch): entire tile outside cutoff
        if (fmin - q.x > q.w || q.x - fmax > q.w) continue;
        float arg = (q.x - f) * q.y;
        float t = arg * arg;
        float e = __expf(-t);
        float v = q.z * arg * e;
        acc += (t <= 9.0f) ? v : 0.0f;
    }
    atomicAdd(&out[b * N + n], acc);
}

extern "C" void kernel_launch(void* const* d_in, const int* in_sizes, int n_in,
                              void* d_out, int out_size, void* d_ws, size_t ws_size,
                              hipStream_t stream) {
    const float* rf     = (const float*)d_in[0];  // [B, M, 3]
    const float* width  = (const float*)d_in[1];  // [B, M]
    const float* A_mean = (const float*)d_in[2];  // [B, M]
    const float* area   = (const float*)d_in[3];  // [M]
    const float* sf     = (const float*)d_in[4];  // [B, N]

    const int M  = in_sizes[3];
    const int BM = in_sizes[1];
    const int B  = BM / M;
    const int N  = in_sizes[4] / B;

    float* out = (float*)d_out;
    float4* params = (float4*)d_ws;   // B*M*16 bytes

    // Kernel 1: params + zero output
    {
        int total = BM;
        int blocks = (total + 255) / 256;
        precompute_kernel<<<blocks, 256, 0, stream>>>(rf, width, A_mean, area, sf,
                                                      params, out, B, M, N, out_size);
    }

    // Kernel 2: main accumulation
    {
        const int MC = 16;                      // m-chunks for parallelism
        int mchunk = (M + MC - 1) / MC;
        int ntiles = (N + 255) / 256;
        dim3 grid(ntiles, MC, B);
        spectra_kernel<<<grid, 256, 0, stream>>>(params, sf, out, M, N, mchunk);
    }
}

// Round 2
// 79.046 us; speedup vs baseline: 1.6769x; 1.6769x over previous
//
#include <hip/hip_runtime.h>
#include <math.h>

#define NW 1e-5f
#define PI_SQRT 1.7724538509055159f
#define TWO_SQRT 1.4142135623730951f
#define CUTOFF 3.0f
#define CHUNK 128   // params per block (m-chunk)
#define TN 512      // field points per tile (2 per thread, 256 threads)

// One fused kernel: each block (tile, m-chunk, batch) computes its chunk's
// per-transition params from raw inputs, window-compacts them into LDS, then
// accumulates 2 field points per thread and atomically adds into d_out.
__global__ __launch_bounds__(256) void spectra_kernel(
    const float* __restrict__ rf,      // [B, M, 3]
    const float* __restrict__ width,   // [B, M]
    const float* __restrict__ A_mean,  // [B, M]
    const float* __restrict__ area,    // [M]
    const float* __restrict__ sf,      // [B, N]
    float* __restrict__ out,           // [B, N] (pre-zeroed)
    int B, int M, int N) {

    __shared__ float4 sp[CHUNK];
    __shared__ int s_cnt;

    const int b = blockIdx.z;
    const int tile = blockIdx.x;
    const int n0 = tile * TN;
    const int tid = (int)threadIdx.x;

    if (tid == 0) s_cnt = 0;

    // this thread's two field points (strided by 256 for coalescing)
    const int n_a = n0 + tid;
    const int n_b = n0 + 256 + tid;
    const float f_a = (n_a < N) ? sf[b * N + n_a] : 3.4e38f;
    const float f_b = (n_b < N) ? sf[b * N + n_b] : 3.4e38f;
    // block's field range (grid is monotone increasing)
    const float fmin = sf[b * N + n0];
    const float fmax = sf[b * N + min(N - 1, n0 + TN - 1)];
    const float sw = (sf[b * N + 1] - sf[b * N]) * 0.5f;

    __syncthreads();   // s_cnt = 0 visible

    // ---- compute + window-compact this block's param chunk into LDS ----
    const int m0 = blockIdx.y * CHUNK;
    if (tid < CHUNK) {
        int m = m0 + tid;
        if (m < M) {
            int idx = b * M + m;
            float r0 = rf[idx * 3 + 0];
            float r1 = rf[idx * 3 + 1];
            float r2 = rf[idx * 3 + 2];
            // exact descending 3-sort via min/max network
            float lo = fminf(r0, r1), hi = fmaxf(r0, r1);
            float B1 = fmaxf(hi, r2);
            float B3 = fminf(lo, r2);
            float B2 = fmaxf(lo, fminf(hi, r2));

            float w = width[idx];
            w = (w > NW) ? w : (w + NW);
            float inv_w = 1.0f / w;
            float d13 = (B1 - B3) * inv_w;
            float d23 = (B2 - B3) * inv_w;
            float d12 = (B1 - B2) * inv_w;
            float add_w_sq = (d13 * d13 + d23 * d23 + d12 * d12) * (1.0f / 9.0f);
            w = (w > 2.0f * NW) ? w : (w + 2.0f * NW);

            float ew = sqrtf(w * w * (1.0f + add_w_sq) + sw * sw);
            ew = (ew < sw * 0.5f) ? ew : (ew + sw * 0.5f);

            float bmean = (B1 + B2 + B3) * (1.0f / 3.0f);
            float c = TWO_SQRT / ew;
            float coef = 2.0f * A_mean[idx] * area[m] * c * c / PI_SQRT;
            float rad = CUTOFF / c + 0.02f;  // |B_mean - f| > rad => all lanes masked

            if (fmin - bmean <= rad && bmean - fmax <= rad) {
                int slot = atomicAdd(&s_cnt, 1);
                sp[slot] = make_float4(bmean, c, coef, 0.0f);
            }
        }
    }
    __syncthreads();
    const int cnt = s_cnt;

    // ---- branch-free inner loop over surviving params (LDS broadcast) ----
    float acc_a = 0.0f, acc_b = 0.0f;
    #pragma unroll 4
    for (int i = 0; i < cnt; ++i) {
        float4 q = sp[i];
        float aa = (q.x - f_a) * q.y;
        float ab = (q.x - f_b) * q.y;
        float ta = aa * aa;
        float tb = ab * ab;
        float va = q.z * aa * __expf(-ta);
        float vb = q.z * ab * __expf(-tb);
        acc_a += (ta <= 9.0f) ? va : 0.0f;
        acc_b += (tb <= 9.0f) ? vb : 0.0f;
    }

    if (n_a < N) atomicAdd(&out[b * N + n_a], acc_a);
    if (n_b < N) atomicAdd(&out[b * N + n_b], acc_b);
}

extern "C" void kernel_launch(void* const* d_in, const int* in_sizes, int n_in,
                              void* d_out, int out_size, void* d_ws, size_t ws_size,
                              hipStream_t stream) {
    const float* rf     = (const float*)d_in[0];  // [B, M, 3]
    const float* width  = (const float*)d_in[1];  // [B, M]
    const float* A_mean = (const float*)d_in[2];  // [B, M]
    const float* area   = (const float*)d_in[3];  // [M]
    const float* sf     = (const float*)d_in[4];  // [B, N]

    const int M  = in_sizes[3];
    const int BM = in_sizes[1];
    const int B  = BM / M;
    const int N  = in_sizes[4] / B;

    float* out = (float*)d_out;

    // zero the accumulator (harness poisons d_out each replay)
    hipMemsetAsync(out, 0, (size_t)out_size * sizeof(float), stream);

    const int ntiles = (N + TN - 1) / TN;
    const int MC     = (M + CHUNK - 1) / CHUNK;
    dim3 grid(ntiles, MC, B);
    spectra_kernel<<<grid, 256, 0, stream>>>(rf, width, A_mean, area, sf, out, B, M, N);
}

// Round 3
// 77.807 us; speedup vs baseline: 1.7036x; 1.0159x over previous
//
#include <hip/hip_runtime.h>
#include <math.h>

#define NW 1e-5f
#define PI_SQRT 1.7724538509055159f
#define TWO_SQRT 1.4142135623730951f
#define CUTOFF 3.0f
#define SQRT_LOG2E 1.2011224087864498f   // sqrt(log2(e))
#define MASK_T 12.983255697783458f       // 9 * log2(e)
#define CHUNK 64    // params per block (m-chunk)
#define TN 256      // field points per tile (2 per thread, 128 threads)
#define NT 128      // threads per block

#if __has_builtin(__builtin_amdgcn_exp2f)
#define FAST_EXP2(x) __builtin_amdgcn_exp2f(x)
#else
#define FAST_EXP2(x) exp2f(x)
#endif

// Fused kernel: block = (field tile, m-chunk, batch). Computes its chunk's
// per-transition params from raw inputs, window-compacts into LDS, then each
// thread accumulates 2 field points and atomically adds into d_out.
// Inner loop uses exp2 directly: constants pre-scaled by sqrt(log2e).
__global__ __launch_bounds__(NT) void spectra_kernel(
    const float* __restrict__ rf,      // [B, M, 3]
    const float* __restrict__ width,   // [B, M]
    const float* __restrict__ A_mean,  // [B, M]
    const float* __restrict__ area,    // [M]
    const float* __restrict__ sf,      // [B, N]
    float* __restrict__ out,           // [B, N] (pre-zeroed)
    int B, int M, int N) {

    __shared__ float4 sp[CHUNK];
    __shared__ int s_cnt;

    const int b = blockIdx.z;
    const int tile = blockIdx.x;
    const int n0 = tile * TN;
    const int tid = (int)threadIdx.x;

    if (tid == 0) s_cnt = 0;

    // this thread's two field points
    const int n_a = n0 + tid;
    const int n_b = n0 + NT + tid;
    const float f_a = (n_a < N) ? sf[b * N + n_a] : 3.4e38f;
    const float f_b = (n_b < N) ? sf[b * N + n_b] : 3.4e38f;
    // block's field range (grid is monotone increasing)
    const float fmin = sf[b * N + n0];
    const float fmax = sf[b * N + min(N - 1, n0 + TN - 1)];
    const float sw = (sf[b * N + 1] - sf[b * N]) * 0.5f;

    __syncthreads();   // s_cnt = 0 visible

    // ---- compute + window-compact this block's param chunk into LDS ----
    const int m0 = blockIdx.y * CHUNK;
    if (tid < CHUNK) {
        int m = m0 + tid;
        if (m < M) {
            int idx = b * M + m;
            float r0 = rf[idx * 3 + 0];
            float r1 = rf[idx * 3 + 1];
            float r2 = rf[idx * 3 + 2];
            // exact descending 3-sort via min/max network
            float lo = fminf(r0, r1), hi = fmaxf(r0, r1);
            float B1 = fmaxf(hi, r2);
            float B3 = fminf(lo, r2);
            float B2 = fmaxf(lo, fminf(hi, r2));

            float w = width[idx];
            w = (w > NW) ? w : (w + NW);
            float inv_w = 1.0f / w;
            float d13 = (B1 - B3) * inv_w;
            float d23 = (B2 - B3) * inv_w;
            float d12 = (B1 - B2) * inv_w;
            float add_w_sq = (d13 * d13 + d23 * d23 + d12 * d12) * (1.0f / 9.0f);
            w = (w > 2.0f * NW) ? w : (w + 2.0f * NW);

            float ew = sqrtf(w * w * (1.0f + add_w_sq) + sw * sw);
            ew = (ew < sw * 0.5f) ? ew : (ew + sw * 0.5f);

            float bmean = (B1 + B2 + B3) * (1.0f / 3.0f);
            float c = TWO_SQRT / ew;
            float coef = 2.0f * A_mean[idx] * area[m] * c * c / PI_SQRT;
            float rad = CUTOFF / c + 0.02f;  // |B_mean - f| > rad => all lanes masked

            if (fmin - bmean <= rad && bmean - fmax <= rad) {
                int slot = atomicAdd(&s_cnt, 1);
                // pre-scale by sqrt(log2e) so inner loop feeds exp2 directly
                sp[slot] = make_float4(bmean, c * SQRT_LOG2E, coef / SQRT_LOG2E, 0.0f);
            }
        }
    }
    __syncthreads();
    const int cnt = s_cnt;

    // ---- branch-free inner loop over surviving params (LDS broadcast) ----
    float acc_a = 0.0f, acc_b = 0.0f;
    #pragma unroll 4
    for (int i = 0; i < cnt; ++i) {
        float4 q = sp[i];
        float ua = (q.x - f_a) * q.y;      // arg * sqrt(log2e)
        float ub = (q.x - f_b) * q.y;
        float ta = -ua * ua;               // -arg^2 * log2e
        float tb = -ub * ub;
        float va = q.z * ua * FAST_EXP2(ta);
        float vb = q.z * ub * FAST_EXP2(tb);
        acc_a += (ta >= -MASK_T) ? va : 0.0f;
        acc_b += (tb >= -MASK_T) ? vb : 0.0f;
    }

    if (n_a < N) atomicAdd(&out[b * N + n_a], acc_a);
    if (n_b < N) atomicAdd(&out[b * N + n_b], acc_b);
}

extern "C" void kernel_launch(void* const* d_in, const int* in_sizes, int n_in,
                              void* d_out, int out_size, void* d_ws, size_t ws_size,
                              hipStream_t stream) {
    const float* rf     = (const float*)d_in[0];  // [B, M, 3]
    const float* width  = (const float*)d_in[1];  // [B, M]
    const float* A_mean = (const float*)d_in[2];  // [B, M]
    const float* area   = (const float*)d_in[3];  // [M]
    const float* sf     = (const float*)d_in[4];  // [B, N]

    const int M  = in_sizes[3];
    const int BM = in_sizes[1];
    const int B  = BM / M;
    const int N  = in_sizes[4] / B;

    float* out = (float*)d_out;

    // zero the accumulator (harness poisons d_out each replay)
    hipMemsetAsync(out, 0, (size_t)out_size * sizeof(float), stream);

    const int ntiles = (N + TN - 1) / TN;
    const int MC     = (M + CHUNK - 1) / CHUNK;
    dim3 grid(ntiles, MC, B);
    spectra_kernel<<<grid, NT, 0, stream>>>(rf, width, A_mean, area, sf, out, B, M, N);
}